// Round 2
// baseline (197.333 us; speedup 1.0000x reference)
//
#include <hip/hip_runtime.h>
#include <hip/hip_bf16.h>

// B=2, T=2048, C=1024, H=16, D=64. Inputs/outputs FLOAT32; compute bf16 MFMA.
// R10: QKV GEMM rebuilt as 256x256/BK=64 8-wave kernel with counted-vmcnt
// 4-phase schedule (T3+T4), granule-XOR LDS swizzle via pre-swizzled global
// source (T2, conflict-free b128), setprio around MFMA clusters (T5).
//   Schedule per K-tile t (buf cur=t&1, prefetch tile t+1 -> buf nxt):
//     [vmcnt(2); barrier]                   <- chunks A0,A2,B0..B3 of t landed
//     ph1: stage A0,A2(t+1); read af(m0-3)+bfa(n0-1); 16 MFMA (0,0)
//     ph2: stage B0,B1(t+1); read bfb(n2-3);          16 MFMA (0,1)
//     [vmcnt(4); barrier]                   <- chunks A1,A3 of t landed
//     ph3: stage B2,B3(t+1); read af(m4-7);           16 MFMA (1,0)
//     ph4: stage A1,A3(t+1);                          16 MFMA (1,1)
//   8 gll16/thread/tile, in-flight depth 8, never vmcnt(0) in the loop.
//   Last tile wrap-prefetches tile 0 (redundant) to keep counts exact.
// Proj GEMM stays on the 128^2 2-phase kernel (256 blocks > 64 blocks at 256^2
// for this underfilled shape). attn/prep unchanged (R9 post-mortem: barrier
// micro-opts on multi-block kernels are null; structural changes only).

typedef __bf16 bf16x8 __attribute__((ext_vector_type(8)));
typedef float  f32x4  __attribute__((ext_vector_type(4)));
#define BF16 __hip_bfloat16

constexpr int Bb = 2, Tt = 2048, Cc = 1024, Hh = 16, Dd = 64;
constexpr float NEG_INF = -1e30f;

__device__ __forceinline__ f32x4 mfma16(bf16x8 a, bf16x8 b, f32x4 c) {
  return __builtin_amdgcn_mfma_f32_16x16x32_bf16(a, b, c, 0, 0, 0);
}

// async global->LDS, 16B per lane; LDS dest = wave-uniform base + lane*16.
__device__ __forceinline__ void gll16(const void* g, void* l) {
  __builtin_amdgcn_global_load_lds((const __attribute__((address_space(1))) void*)g,
                                   (__attribute__((address_space(3))) void*)l,
                                   16, 0, 0);
}

// XOR swizzle for 64-col LDS tiles: conflict-free b128 reads along rows.
__device__ __forceinline__ int swz64(int r, int c) {
  return r * 64 + ((((c >> 3) ^ r) & 7) << 3) + (c & 7);
}

// K-row permutation: key kr -> LDS row so S^T C-layout regs concat into
// natural-kc K=32 A-frags. kr = cc*32+q*8+t'*4+r -> row (cc*2+t')*16+q*4+r.
__device__ __forceinline__ int kperm(int kr) {
  return (((kr >> 5) << 1) + ((kr >> 2) & 1)) * 16 + (((kr >> 3) & 3) << 2) + (kr & 3);
}

// Fused prep: blocks [0,2048) cast x f32->bf16 (8/thread);
// [2048,5120) transpose+cast W_attn; [5120,6144) transpose+cast W_proj.
__global__ void prep_kernel(const float* __restrict__ x, BF16* __restrict__ xb,
                            const float* __restrict__ Wa, BF16* __restrict__ WaT,
                            const float* __restrict__ Wp, BF16* __restrict__ WpT) {
  __shared__ float tile[32][33];
  const int bx = blockIdx.x, tid = threadIdx.x;
  if (bx < 2048) {
    const int i = (bx * 256 + tid) * 8;
    const float4 a = *(const float4*)&x[i];
    const float4 b = *(const float4*)&x[i + 4];
    BF16 o[8];
    o[0] = __float2bfloat16(a.x); o[1] = __float2bfloat16(a.y);
    o[2] = __float2bfloat16(a.z); o[3] = __float2bfloat16(a.w);
    o[4] = __float2bfloat16(b.x); o[5] = __float2bfloat16(b.y);
    o[6] = __float2bfloat16(b.z); o[7] = __float2bfloat16(b.w);
    *(uint4*)&xb[i] = *(const uint4*)o;
    return;
  }
  const float* in; BF16* outT; int K, N, gx, gy;
  if (bx < 5120) {
    const int idx = bx - 2048;
    in = Wa; outT = WaT; K = 1024; N = 3072; gx = idx % 96; gy = idx / 96;
  } else {
    const int idx = bx - 5120;
    in = Wp; outT = WpT; K = 1024; N = 1024; gx = idx % 32; gy = idx / 32;
  }
  const int n0 = gx * 32, k0 = gy * 32;
  const int tx = tid & 31, ty = tid >> 5;
#pragma unroll
  for (int i = ty; i < 32; i += 8) tile[i][tx] = in[(size_t)(k0 + i) * N + (n0 + tx)];
  __syncthreads();
#pragma unroll
  for (int i = ty; i < 32; i += 8)
    outT[(size_t)(n0 + i) * K + (k0 + tx)] = __float2bfloat16(tile[tx][i]);
}

// ---------------------------------------------------------------------------
// QKV GEMM: C[m][n] = sum_k A[m][k]*Bt[n][k] + bias[n], M=4096 N=3072 K=1024.
// 256x256 tile, BK=64, 8 waves (2M x 4N), 512 thr, LDS 2x(32KB A + 32KB B).
// Scatter: q/k [B,H,T,D] bf16 (q pre-scaled 1/8), v transposed [B,H,D,T].
// ---------------------------------------------------------------------------
__global__ __launch_bounds__(512, 2) void gemm256_qkv(const BF16* __restrict__ A,
                                                      const BF16* __restrict__ Bt,
                                                      const float* __restrict__ bias,
                                                      BF16* __restrict__ oq,
                                                      BF16* __restrict__ ok,
                                                      BF16* __restrict__ ov) {
  __shared__ alignas(16) BF16 sAs[2][16384];  // [buf][256 rows][64 cols] swizzled
  __shared__ alignas(16) BF16 sBs[2][16384];
  const int tid = threadIdx.x;
  const int wave = tid >> 6, lane = tid & 63;
  const int quad = lane >> 4, l16 = lane & 15;
  const int wr = wave >> 2, wc = wave & 3;      // 2 M-waves x 4 N-waves
  const int wr128 = wr * 128, wc64 = wc * 64;
  const int bm = blockIdx.y * 256, bn = blockIdx.x * 256;
  const int sw = l16 & 7;                       // read-side swizzle key (row&7)

  // Staging: chunk c = 64 rows. Thread -> row (tid>>3) in chunk, physical
  // granule tid&7; global source col pre-swizzled so linear gll16 writes land
  // the swizzled layout: logical granule = (tid&7) ^ (row&7).
  const int srow = tid >> 3;
  const int sgl = (tid & 7) ^ (srow & 7);
  const BF16* gA = &A[(size_t)(bm + srow) * 1024 + sgl * 8];
  const BF16* gB = &Bt[(size_t)(bn + srow) * 1024 + sgl * 8];

#define STAGE_A(b, c, kc) \
  gll16(gA + (size_t)(c) * 64 * 1024 + (kc), &sAs[b][(c) * 4096 + wave * 512])
#define STAGE_B(b, c, kc) \
  gll16(gB + (size_t)(c) * 64 * 1024 + (kc), &sBs[b][(c) * 4096 + wave * 512])

  f32x4 acc[8][4];
#pragma unroll
  for (int m = 0; m < 8; ++m)
#pragma unroll
    for (int n = 0; n < 4; ++n) acc[m][n] = f32x4{0.f, 0.f, 0.f, 0.f};

  // prologue: tile 0 -> buf 0, first-needed order (A0,A2,B0..B3 then A1,A3)
  STAGE_A(0, 0, 0); STAGE_A(0, 2, 0);
  STAGE_B(0, 0, 0); STAGE_B(0, 1, 0); STAGE_B(0, 2, 0); STAGE_B(0, 3, 0);
  STAGE_A(0, 1, 0); STAGE_A(0, 3, 0);

  for (int t = 0; t < 16; ++t) {
    const int cur = t & 1, nxt = cur ^ 1;
    const int kc = ((t + 1) & 15) * 64;  // wrap keeps vmcnt counts exact
    const BF16* sAc = sAs[cur];
    const BF16* sBc = sBs[cur];

    // tile start: A0,A2,B0..B3 of tile t landed (leaves t's A1,A3 in flight)
    asm volatile("s_waitcnt vmcnt(2)" ::: "memory");
    __builtin_amdgcn_s_barrier();
    asm volatile("" ::: "memory");

    // ---- phase 1: quadrant (m0-3, n0-1)
    STAGE_A(nxt, 0, kc); STAGE_A(nxt, 2, kc);
    bf16x8 af[4][2], bfa[2][2], bfb[2][2];
#pragma unroll
    for (int m = 0; m < 4; ++m)
#pragma unroll
      for (int h = 0; h < 2; ++h)
        af[m][h] = *(const bf16x8*)
            &sAc[(wr128 + m * 16 + l16) * 64 + (((h * 4 + quad) ^ sw) << 3)];
#pragma unroll
    for (int n = 0; n < 2; ++n)
#pragma unroll
      for (int h = 0; h < 2; ++h)
        bfa[n][h] = *(const bf16x8*)
            &sBc[(wc64 + n * 16 + l16) * 64 + (((h * 4 + quad) ^ sw) << 3)];
    __builtin_amdgcn_s_setprio(1);
#pragma unroll
    for (int m = 0; m < 4; ++m)
#pragma unroll
      for (int n = 0; n < 2; ++n) {
        acc[m][n] = mfma16(af[m][0], bfa[n][0], acc[m][n]);
        acc[m][n] = mfma16(af[m][1], bfa[n][1], acc[m][n]);
      }
    __builtin_amdgcn_s_setprio(0);

    // ---- phase 2: quadrant (m0-3, n2-3)
    STAGE_B(nxt, 0, kc); STAGE_B(nxt, 1, kc);
#pragma unroll
    for (int n = 0; n < 2; ++n)
#pragma unroll
      for (int h = 0; h < 2; ++h)
        bfb[n][h] = *(const bf16x8*)
            &sBc[(wc64 + 32 + n * 16 + l16) * 64 + (((h * 4 + quad) ^ sw) << 3)];
    __builtin_amdgcn_s_setprio(1);
#pragma unroll
    for (int m = 0; m < 4; ++m)
#pragma unroll
      for (int n = 0; n < 2; ++n) {
        acc[m][2 + n] = mfma16(af[m][0], bfb[n][0], acc[m][2 + n]);
        acc[m][2 + n] = mfma16(af[m][1], bfb[n][1], acc[m][2 + n]);
      }
    __builtin_amdgcn_s_setprio(0);

    // mid-tile: A1,A3 of tile t landed (leaves t+1's A0,A2,B0,B1 in flight)
    asm volatile("s_waitcnt vmcnt(4)" ::: "memory");
    __builtin_amdgcn_s_barrier();
    asm volatile("" ::: "memory");

    // ---- phase 3: quadrant (m4-7, n0-1)
    STAGE_B(nxt, 2, kc); STAGE_B(nxt, 3, kc);
#pragma unroll
    for (int m = 0; m < 4; ++m)
#pragma unroll
      for (int h = 0; h < 2; ++h)
        af[m][h] = *(const bf16x8*)
            &sAc[(wr128 + 64 + m * 16 + l16) * 64 + (((h * 4 + quad) ^ sw) << 3)];
    __builtin_amdgcn_s_setprio(1);
#pragma unroll
    for (int m = 0; m < 4; ++m)
#pragma unroll
      for (int n = 0; n < 2; ++n) {
        acc[4 + m][n] = mfma16(af[m][0], bfa[n][0], acc[4 + m][n]);
        acc[4 + m][n] = mfma16(af[m][1], bfa[n][1], acc[4 + m][n]);
      }
    __builtin_amdgcn_s_setprio(0);

    // ---- phase 4: quadrant (m4-7, n2-3)
    STAGE_A(nxt, 1, kc); STAGE_A(nxt, 3, kc);
    __builtin_amdgcn_s_setprio(1);
#pragma unroll
    for (int m = 0; m < 4; ++m)
#pragma unroll
      for (int n = 0; n < 2; ++n) {
        acc[4 + m][2 + n] = mfma16(af[m][0], bfb[n][0], acc[4 + m][2 + n]);
        acc[4 + m][2 + n] = mfma16(af[m][1], bfb[n][1], acc[4 + m][2 + n]);
      }
    __builtin_amdgcn_s_setprio(0);
  }
#undef STAGE_A
#undef STAGE_B

  // epilogue: gm = bm + wr*128 + m*16 + quad*4 + r; gn = bn + wc*64 + n*16 + l16
#pragma unroll
  for (int n = 0; n < 4; ++n) {
    const int gn = bn + wc64 + n * 16 + l16;
    const float bsv = bias[gn];
    const int which = (bn + wc64 + n * 16) >> 10;  // wave-uniform per n
    const int c = gn & 1023;
    const int hh = c >> 6, dd = c & 63;
#pragma unroll
    for (int m = 0; m < 8; ++m) {
      const int gm0 = bm + wr128 + m * 16 + quad * 4;  // 4-aligned
      const int bb = gm0 >> 11, tk0 = gm0 & 2047;
      const size_t bh = (size_t)(bb * Hh + hh);
      if (which == 2) {
        // V: transposed [B,H,D,T]; 4 r-accs contiguous in t -> one 8B store.
        BF16 tmp[4];
#pragma unroll
        for (int r = 0; r < 4; ++r) tmp[r] = __float2bfloat16(acc[m][n][r] + bsv);
        *(uint2*)&ov[(bh * Dd + dd) * Tt + tk0] = *(const uint2*)tmp;
      } else {
        BF16* dst = (which == 0) ? oq : ok;
        const float scale = (which == 0) ? 0.125f : 1.0f;  // fold 1/sqrt(D) into q
#pragma unroll
        for (int r = 0; r < 4; ++r)
          dst[(bh * Tt + tk0 + r) * Dd + dd] =
              __float2bfloat16((acc[m][n][r] + bsv) * scale);
      }
    }
  }
}

// 128^2 2-phase GEMM, used for the proj matmul (MODE 1: f32 out).
template <int MODE>
__global__ __launch_bounds__(256) void gemm_bt(const BF16* __restrict__ A,
                                               const BF16* __restrict__ Bt,
                                               const float* __restrict__ bias,
                                               float* __restrict__ fout,
                                               int Ndim, int Kdim) {
  __shared__ alignas(16) BF16 sA[128 * 32];
  __shared__ alignas(16) BF16 sB[128 * 32];
  const int tid = threadIdx.x;
  const int wave = tid >> 6, lane = tid & 63;
  const int quad = lane >> 4, l16 = lane & 15;
  const int wm = (wave >> 1) * 64, wn = (wave & 1) * 64;
  const int bm = blockIdx.y * 128, bn = blockIdx.x * 128;

  f32x4 acc[4][4];
#pragma unroll
  for (int i = 0; i < 4; ++i)
#pragma unroll
    for (int j = 0; j < 4; ++j) acc[i][j] = f32x4{0.f, 0.f, 0.f, 0.f};

  const int rowA = wave * 32 + (lane >> 2);
  const int sub8 = (lane & 3) * 8;
  const BF16* gA0 = &A[(size_t)(bm + rowA) * Kdim + sub8];
  const BF16* gB0 = &Bt[(size_t)(bn + rowA) * Kdim + sub8];
  const size_t rstep16 = (size_t)16 * Kdim;
  BF16* lA0 = &sA[wave * 1024];
  BF16* lA1 = &sA[wave * 1024 + 512];
  BF16* lB0 = &sB[wave * 1024];
  BF16* lB1 = &sB[wave * 1024 + 512];

  for (int k0 = 0; k0 < Kdim; k0 += 32) {
    __syncthreads();
    gll16(gA0 + k0, lA0);
    gll16(gA0 + rstep16 + k0, lA1);
    gll16(gB0 + k0, lB0);
    gll16(gB0 + rstep16 + k0, lB1);
    __syncthreads();

    bf16x8 af[4], bf_[4];
#pragma unroll
    for (int i = 0; i < 4; ++i)
      af[i] = *(const bf16x8*)&sA[(wm + i * 16 + l16) * 32 + quad * 8];
#pragma unroll
    for (int j = 0; j < 4; ++j)
      bf_[j] = *(const bf16x8*)&sB[(wn + j * 16 + l16) * 32 + quad * 8];
#pragma unroll
    for (int i = 0; i < 4; ++i)
#pragma unroll
      for (int j = 0; j < 4; ++j) acc[i][j] = mfma16(af[i], bf_[j], acc[i][j]);
  }

#pragma unroll
  for (int j = 0; j < 4; ++j) {
    const int gn = bn + wn + j * 16 + l16;
    const float bsv = bias[gn];
#pragma unroll
    for (int i = 0; i < 4; ++i)
#pragma unroll
      for (int r = 0; r < 4; ++r) {
        const int gm = bm + wm + i * 16 + quad * 4 + r;
        fout[(size_t)gm * Ndim + gn] = acc[i][j][r] + bsv;
      }
  }
}

// Causal flash attention, no-max softmax p = exp(S-12). (unchanged from R9)
__global__ __launch_bounds__(256) void attn_kernel(const BF16* __restrict__ qg,
                                                   const BF16* __restrict__ kg,
                                                   const BF16* __restrict__ vtg,
                                                   BF16* __restrict__ yb) {
  __shared__ alignas(16) BF16 sK[2 * 64 * 64];  // [bank][perm_key][d], swizzled
  __shared__ alignas(16) BF16 sV[2 * 64 * 64];  // [bank][d][key], swizzled
  const int pr = blockIdx.x, h = blockIdx.y, b = blockIdx.z;
  const int tid = threadIdx.x;
  const int wave = tid >> 6, lane = tid & 63;
  const int quad = lane >> 4, l16 = lane & 15;
  const int qs = (wave >> 1) ? (63 - pr) : pr;  // this wave's 32-row strip
  const int sub = wave & 1;                     // 16-row chunk within strip
  const int jt_diag = qs >> 1;                  // wave active for jt <= jt_diag
  const int jt_max = (63 - pr) >> 1;            // block loop bound
  const size_t base = ((size_t)(b * Hh + h)) * Tt * Dd;
  const int qrow0 = qs * 32 + sub * 16;

  // Q fragment (B-operand: lane n=l16 holds Q[qrow0+l16][k=quad*8+j])
  bf16x8 qf0, qf1;
  {
    const size_t off = base + (size_t)(qrow0 + l16) * Dd;
    qf0 = *(const bf16x8*)&qg[off + quad * 8];
    qf1 = *(const bf16x8*)&qg[off + 32 + quad * 8];
  }

  bf16x8 ones8;
#pragma unroll
  for (int j = 0; j < 8; ++j) ones8[j] = (__bf16)1.0f;

  f32x4 o[4], oL;
#pragma unroll
  for (int i = 0; i < 4; ++i) o[i] = f32x4{0.f, 0.f, 0.f, 0.f};
  oL = f32x4{0.f, 0.f, 0.f, 0.f};

  const int krow = tid >> 2, kcg = (tid & 3) * 16;
  const int kprow = kperm(krow);
  const int wK0 = swz64(kprow, kcg), wK1 = swz64(kprow, kcg + 8);
  const int wV0 = swz64(krow, kcg), wV1 = swz64(krow, kcg + 8);

  // prefetch tile 0 into registers
  uint4 rk0, rk1, rv0, rv1;
  {
    const uint4* pk = (const uint4*)&kg[base + (size_t)krow * Dd + kcg];
    const uint4* pv = (const uint4*)&vtg[base + (size_t)krow * Tt + kcg];
    rk0 = pk[0]; rk1 = pk[1];
    rv0 = pv[0]; rv1 = pv[1];
  }

  for (int jt = 0; jt <= jt_max; ++jt) {
    BF16* sKb = &sK[(jt & 1) * 4096];
    BF16* sVb = &sV[(jt & 1) * 4096];
    *(uint4*)&sKb[wK0] = rk0;
    *(uint4*)&sKb[wK1] = rk1;
    *(uint4*)&sVb[wV0] = rv0;
    *(uint4*)&sVb[wV1] = rv1;
    if (jt < jt_max) {  // prefetch next tile; loads fly during compute
      const int kb2 = (jt + 1) * 64;
      const uint4* nk = (const uint4*)&kg[base + (size_t)(kb2 + krow) * Dd + kcg];
      const uint4* nv = (const uint4*)&vtg[base + (size_t)krow * Tt + kb2 + kcg];
      rk0 = nk[0]; rk1 = nk[1];
      rv0 = nv[0]; rv1 = nv[1];
    }
    __syncthreads();  // bank jt&1 visible; also orders next write of other bank

    if (jt > jt_diag) continue;  // wave past its causal range (barriers stay matched)
    const int kb = jt * 64;

    // S^T tile t: A = permuted K rows t*16+l16, B = Q. C-layout: col l16 = q,
    // row quad*4+r -> key kc = kb + (t>>1)*32 + quad*8 + (t&1)*4 + r.
    f32x4 sS[4];
    __builtin_amdgcn_s_setprio(1);
#pragma unroll
    for (int t = 0; t < 4; ++t) {
      const bf16x8 kf0 = *(const bf16x8*)&sKb[swz64(t * 16 + l16, quad * 8)];
      const bf16x8 kf1 = *(const bf16x8*)&sKb[swz64(t * 16 + l16, 32 + quad * 8)];
      sS[t] = mfma16(kf0, qf0, f32x4{0.f, 0.f, 0.f, 0.f});
      sS[t] = mfma16(kf1, qf1, sS[t]);
    }
    __builtin_amdgcn_s_setprio(0);

    if (jt == jt_diag) {  // boundary tile: causal mask
      const int q = qrow0 + l16;
#pragma unroll
      for (int t = 0; t < 4; ++t) {
        const int kc0 = kb + (t >> 1) * 32 + quad * 8 + (t & 1) * 4;
#pragma unroll
        for (int r = 0; r < 4; ++r)
          if (kc0 + r > q) sS[t][r] = NEG_INF;
      }
    }

    // p = exp(S-12) packed into K=32 A-frags (kc = cc*32 + quad*8 + j)
    bf16x8 pf[2];
#pragma unroll
    for (int cc = 0; cc < 2; ++cc)
#pragma unroll
      for (int j = 0; j < 8; ++j)
        pf[cc][j] = (__bf16)__expf(sS[cc * 2 + (j >> 2)][j & 3] - 12.0f);

    // PV + rowsum, K=32. vb: V^T row dt*16+l16, cols cc*32+quad*8.
    __builtin_amdgcn_s_setprio(1);
#pragma unroll
    for (int cc = 0; cc < 2; ++cc) {
#pragma unroll
      for (int dt = 0; dt < 4; ++dt) {
        const bf16x8 vb =
            *(const bf16x8*)&sVb[swz64(dt * 16 + l16, cc * 32 + quad * 8)];
        o[dt] = mfma16(pf[cc], vb, o[dt]);
      }
      oL = mfma16(pf[cc], ones8, oL);
    }
    __builtin_amdgcn_s_setprio(0);
  }

  // epilogue: C-layout row quad*4+r = q, col dt*16+l16 = d
#pragma unroll
  for (int r = 0; r < 4; ++r) {
    const float inv = 1.0f / oL[r];
    const int trow = qrow0 + quad * 4 + r;
#pragma unroll
    for (int dt = 0; dt < 4; ++dt)
      yb[((size_t)(b * Tt + trow)) * Cc + h * Dd + dt * 16 + l16] =
          __float2bfloat16(o[dt][r] * inv);
  }
}

extern "C" void kernel_launch(void* const* d_in, const int* in_sizes, int n_in,
                              void* d_out, int out_size, void* d_ws, size_t ws_size,
                              hipStream_t stream) {
  (void)in_sizes; (void)n_in; (void)out_size; (void)ws_size;
  const float* x      = (const float*)d_in[0];
  const float* W_attn = (const float*)d_in[1];
  const float* b_attn = (const float*)d_in[2];
  const float* W_proj = (const float*)d_in[3];
  const float* b_proj = (const float*)d_in[4];
  float* out = (float*)d_out;

  constexpr size_t SZ_WA = (size_t)3072 * 1024;
  constexpr size_t SZ_WP = (size_t)1024 * 1024;
  constexpr size_t SZ_X  = (size_t)4096 * 1024;
  constexpr size_t SZ_T  = (size_t)Bb * Hh * Tt * Dd;

  BF16* ws   = (BF16*)d_ws;
  BF16* wtAb = ws;
  BF16* wtPb = wtAb + SZ_WA;
  BF16* xb   = wtPb + SZ_WP;
  BF16* q    = xb + SZ_X;
  BF16* k    = q + SZ_T;
  BF16* vt   = k + SZ_T;
  BF16* yb   = vt + SZ_T;

  prep_kernel<<<dim3(6144), 256, 0, stream>>>(x, xb, W_attn, wtAb, W_proj, wtPb);
  gemm256_qkv<<<dim3(12, 16), 512, 0, stream>>>(xb, wtAb, b_attn, q, k, vt);
  attn_kernel<<<dim3(32, 16, 2), 256, 0, stream>>>(q, k, vt, yb);
  gemm_bt<1><<<dim3(8, 32), 256, 0, stream>>>(yb, wtPb, b_proj, out, 1024, 1024);
}

// Round 3
// 182.176 us; speedup vs baseline: 1.0832x; 1.0832x over previous
//
#include <hip/hip_runtime.h>
#include <hip/hip_bf16.h>

// B=2, T=2048, C=1024, H=16, D=64. Inputs/outputs FLOAT32; compute bf16 MFMA.
// R11: revert R10's 256^2 port (coarse-phase 8ph regressed: 511 TF, 72% stall
// — m196/m232 reproduced). Instead:
//  - gemm_bt: 128^2 tile, BK 32->64 (2-phase stall S amortized over 2x MFMA;
//    m233: S ~72% of iter -> predicted ~1.4x). LDS 32KB keeps 3 blocks/CU
//    (m132's BK=128 failure was the 64KB occupancy cliff, avoided here).
//  - gemm_bt: full 8-granule XOR LDS swizzle (phys = logical ^ (row&7)),
//    staged via pre-swizzled GLOBAL source so gll16 dest stays linear
//    (rule #21; this exact scheme measured 0 conflicts in R10).
//  - attn: bijective XCD chunk swizzle (T1): each XCD gets 4 (b,h) groups
//    -> 2MB K/V working set fits its private 4MB L2 (vs ~400MB L3 re-reads).
//  - attn compute path unchanged (R9 lesson: micro-opts there are null).

typedef __bf16 bf16x8 __attribute__((ext_vector_type(8)));
typedef float  f32x4  __attribute__((ext_vector_type(4)));
#define BF16 __hip_bfloat16

constexpr int Bb = 2, Tt = 2048, Cc = 1024, Hh = 16, Dd = 64;
constexpr float NEG_INF = -1e30f;

__device__ __forceinline__ f32x4 mfma16(bf16x8 a, bf16x8 b, f32x4 c) {
  return __builtin_amdgcn_mfma_f32_16x16x32_bf16(a, b, c, 0, 0, 0);
}

// async global->LDS, 16B per lane; LDS dest = wave-uniform base + lane*16.
__device__ __forceinline__ void gll16(const void* g, void* l) {
  __builtin_amdgcn_global_load_lds((const __attribute__((address_space(1))) void*)g,
                                   (__attribute__((address_space(3))) void*)l,
                                   16, 0, 0);
}

// XOR swizzle for 64-col LDS tiles: conflict-free b128 reads along rows.
__device__ __forceinline__ int swz64(int r, int c) {
  return r * 64 + ((((c >> 3) ^ r) & 7) << 3) + (c & 7);
}

// K-row permutation: key kr -> LDS row so S^T C-layout regs concat into
// natural-kc K=32 A-frags. kr = cc*32+q*8+t'*4+r -> row (cc*2+t')*16+q*4+r.
__device__ __forceinline__ int kperm(int kr) {
  return (((kr >> 5) << 1) + ((kr >> 2) & 1)) * 16 + (((kr >> 3) & 3) << 2) + (kr & 3);
}

// Fused prep: blocks [0,2048) cast x f32->bf16 (8/thread);
// [2048,5120) transpose+cast W_attn; [5120,6144) transpose+cast W_proj.
__global__ void prep_kernel(const float* __restrict__ x, BF16* __restrict__ xb,
                            const float* __restrict__ Wa, BF16* __restrict__ WaT,
                            const float* __restrict__ Wp, BF16* __restrict__ WpT) {
  __shared__ float tile[32][33];
  const int bx = blockIdx.x, tid = threadIdx.x;
  if (bx < 2048) {
    const int i = (bx * 256 + tid) * 8;
    const float4 a = *(const float4*)&x[i];
    const float4 b = *(const float4*)&x[i + 4];
    BF16 o[8];
    o[0] = __float2bfloat16(a.x); o[1] = __float2bfloat16(a.y);
    o[2] = __float2bfloat16(a.z); o[3] = __float2bfloat16(a.w);
    o[4] = __float2bfloat16(b.x); o[5] = __float2bfloat16(b.y);
    o[6] = __float2bfloat16(b.z); o[7] = __float2bfloat16(b.w);
    *(uint4*)&xb[i] = *(const uint4*)o;
    return;
  }
  const float* in; BF16* outT; int K, N, gx, gy;
  if (bx < 5120) {
    const int idx = bx - 2048;
    in = Wa; outT = WaT; K = 1024; N = 3072; gx = idx % 96; gy = idx / 96;
  } else {
    const int idx = bx - 5120;
    in = Wp; outT = WpT; K = 1024; N = 1024; gx = idx % 32; gy = idx / 32;
  }
  const int n0 = gx * 32, k0 = gy * 32;
  const int tx = tid & 31, ty = tid >> 5;
#pragma unroll
  for (int i = ty; i < 32; i += 8) tile[i][tx] = in[(size_t)(k0 + i) * N + (n0 + tx)];
  __syncthreads();
#pragma unroll
  for (int i = ty; i < 32; i += 8)
    outT[(size_t)(n0 + i) * K + (k0 + tx)] = __float2bfloat16(tile[tx][i]);
}

// C[m][n] = sum_k A[m][k]*Bt[n][k] + bias[n].  128x128 tile, BK=64, 2-phase.
// LDS [128 rows][64 cols], granule-XOR swizzled: physical 8-elem granule p of
// row r holds logical granule p^(r&7). Staged by pre-swizzling the global
// source column (gll16 LDS dest must stay linear). Reads: b128 at
// col ((g)^(l16&7))*8 -> 2 accesses/bank/16-lane group = conflict-free.
// MODE 0: scatter q/k [B,H,T,D] bf16 (q pre-scaled 1/8), V transposed
// [B,H,D,T] (8B packed stores). MODE 1: f32 out.
template <int MODE>
__global__ __launch_bounds__(256) void gemm_bt(const BF16* __restrict__ A,
                                               const BF16* __restrict__ Bt,
                                               const float* __restrict__ bias,
                                               BF16* __restrict__ oq,
                                               BF16* __restrict__ ok,
                                               BF16* __restrict__ ov,
                                               float* __restrict__ fout,
                                               int Ndim, int Kdim) {
  __shared__ alignas(16) BF16 sA[128 * 64];
  __shared__ alignas(16) BF16 sB[128 * 64];
  const int tid = threadIdx.x;
  const int wave = tid >> 6, lane = tid & 63;
  const int quad = lane >> 4, l16 = lane & 15;
  const int wm = (wave >> 1) * 64, wn = (wave & 1) * 64;
  const int bm = blockIdx.y * 128, bn = blockIdx.x * 128;
  const int sw = l16 & 7;  // read-side swizzle key (= row&7 for row base%16==0)

  f32x4 acc[4][4];
#pragma unroll
  for (int i = 0; i < 4; ++i)
#pragma unroll
    for (int j = 0; j < 4; ++j) acc[i][j] = f32x4{0.f, 0.f, 0.f, 0.f};

  // Staging: wave stages rows wave*32 + s*8 + (lane>>3), s=0..3.
  // Physical granule lane&7 must hold logical (lane&7)^(row&7); row&7 =
  // (lane>>3)&7 independent of wave/s -> single pre-swizzled source pointer.
  const int srow = wave * 32 + (lane >> 3);
  const int sgl = (lane ^ (lane >> 3)) & 7;
  const BF16* gA0 = &A[(size_t)(bm + srow) * Kdim + sgl * 8];
  const BF16* gB0 = &Bt[(size_t)(bn + srow) * Kdim + sgl * 8];
  const size_t rstep8 = (size_t)8 * Kdim;

  for (int k0 = 0; k0 < Kdim; k0 += 64) {
    __syncthreads();  // WAR: all waves done reading previous tile
#pragma unroll
    for (int s = 0; s < 4; ++s) {
      gll16(gA0 + s * rstep8 + k0, &sA[wave * 2048 + s * 512]);
      gll16(gB0 + s * rstep8 + k0, &sB[wave * 2048 + s * 512]);
    }
    __syncthreads();  // compiler drains vmcnt(0) before barrier -> tile visible

#pragma unroll
    for (int h = 0; h < 2; ++h) {
      bf16x8 af[4], bf_[4];
#pragma unroll
      for (int i = 0; i < 4; ++i)
        af[i] = *(const bf16x8*)
            &sA[(wm + i * 16 + l16) * 64 + (((h * 4 + quad) ^ sw) << 3)];
#pragma unroll
      for (int j = 0; j < 4; ++j)
        bf_[j] = *(const bf16x8*)
            &sB[(wn + j * 16 + l16) * 64 + (((h * 4 + quad) ^ sw) << 3)];
#pragma unroll
      for (int i = 0; i < 4; ++i)
#pragma unroll
        for (int j = 0; j < 4; ++j) acc[i][j] = mfma16(af[i], bf_[j], acc[i][j]);
    }
  }

#pragma unroll
  for (int j = 0; j < 4; ++j) {
    const int gn = bn + wn + j * 16 + l16;
    const float bsv = bias[gn];
    if (MODE == 1) {
#pragma unroll
      for (int i = 0; i < 4; ++i)
#pragma unroll
        for (int r = 0; r < 4; ++r) {
          const int gm = bm + wm + i * 16 + quad * 4 + r;
          fout[(size_t)gm * Ndim + gn] = acc[i][j][r] + bsv;
        }
    } else {
      // which is wave-uniform per j: gn span is 16-aligned, never crosses 1024.
      const int which = (bn + wn + j * 16) >> 10;
      const int c = gn & 1023;
      const int hh = c >> 6, dd = c & 63;
#pragma unroll
      for (int i = 0; i < 4; ++i) {
        const int gm0 = bm + wm + i * 16 + quad * 4;  // 4-aligned: bb/tk0 uniform over r
        const int bb = gm0 >> 11, tk0 = gm0 & 2047;
        const size_t bh = (size_t)(bb * Hh + hh);
        if (which == 2) {
          // V: transposed [B,H,D,T]; r-accs are contiguous t -> one 8B store.
          BF16 tmp[4];
#pragma unroll
          for (int r = 0; r < 4; ++r) tmp[r] = __float2bfloat16(acc[i][j][r] + bsv);
          *(uint2*)&ov[(bh * Dd + dd) * Tt + tk0] = *(const uint2*)tmp;
        } else {
          BF16* dst = (which == 0) ? oq : ok;
          const float scale = (which == 0) ? 0.125f : 1.0f;  // fold 1/sqrt(D) into q
#pragma unroll
          for (int r = 0; r < 4; ++r)
            dst[(bh * Tt + tk0 + r) * Dd + dd] =
                __float2bfloat16((acc[i][j][r] + bsv) * scale);
        }
      }
    }
  }
}

// Causal flash attention, no-max softmax p = exp(S-12).
// Flat grid 1024 with bijective XCD chunk swizzle: hardware round-robins
// blockIdx%8 across XCDs, so remap id -> (id&7)*128 + (id>>3): each XCD gets
// 128 consecutive work ids = 4 (b,h) groups = 2MB K/V, L2-resident.
__global__ __launch_bounds__(256) void attn_kernel(const BF16* __restrict__ qg,
                                                   const BF16* __restrict__ kg,
                                                   const BF16* __restrict__ vtg,
                                                   BF16* __restrict__ yb) {
  __shared__ alignas(16) BF16 sK[2 * 64 * 64];  // [bank][perm_key][d], swizzled
  __shared__ alignas(16) BF16 sV[2 * 64 * 64];  // [bank][d][key], swizzled
  const int id = blockIdx.x;
  const int swz = ((id & 7) << 7) + (id >> 3);  // bijective (1024 % 8 == 0)
  const int pr = swz & 31, h = (swz >> 5) & 15, b = swz >> 9;
  const int tid = threadIdx.x;
  const int wave = tid >> 6, lane = tid & 63;
  const int quad = lane >> 4, l16 = lane & 15;
  const int qs = (wave >> 1) ? (63 - pr) : pr;  // this wave's 32-row strip
  const int sub = wave & 1;                     // 16-row chunk within strip
  const int jt_diag = qs >> 1;                  // wave active for jt <= jt_diag
  const int jt_max = (63 - pr) >> 1;            // block loop bound
  const size_t base = ((size_t)(b * Hh + h)) * Tt * Dd;
  const int qrow0 = qs * 32 + sub * 16;

  // Q fragment (B-operand: lane n=l16 holds Q[qrow0+l16][k=quad*8+j])
  bf16x8 qf0, qf1;
  {
    const size_t off = base + (size_t)(qrow0 + l16) * Dd;
    qf0 = *(const bf16x8*)&qg[off + quad * 8];
    qf1 = *(const bf16x8*)&qg[off + 32 + quad * 8];
  }

  bf16x8 ones8;
#pragma unroll
  for (int j = 0; j < 8; ++j) ones8[j] = (__bf16)1.0f;

  f32x4 o[4], oL;
#pragma unroll
  for (int i = 0; i < 4; ++i) o[i] = f32x4{0.f, 0.f, 0.f, 0.f};
  oL = f32x4{0.f, 0.f, 0.f, 0.f};

  const int krow = tid >> 2, kcg = (tid & 3) * 16;
  const int kprow = kperm(krow);
  const int wK0 = swz64(kprow, kcg), wK1 = swz64(kprow, kcg + 8);
  const int wV0 = swz64(krow, kcg), wV1 = swz64(krow, kcg + 8);

  // prefetch tile 0 into registers
  uint4 rk0, rk1, rv0, rv1;
  {
    const uint4* pk = (const uint4*)&kg[base + (size_t)krow * Dd + kcg];
    const uint4* pv = (const uint4*)&vtg[base + (size_t)krow * Tt + kcg];
    rk0 = pk[0]; rk1 = pk[1];
    rv0 = pv[0]; rv1 = pv[1];
  }

  for (int jt = 0; jt <= jt_max; ++jt) {
    BF16* sKb = &sK[(jt & 1) * 4096];
    BF16* sVb = &sV[(jt & 1) * 4096];
    *(uint4*)&sKb[wK0] = rk0;
    *(uint4*)&sKb[wK1] = rk1;
    *(uint4*)&sVb[wV0] = rv0;
    *(uint4*)&sVb[wV1] = rv1;
    if (jt < jt_max) {  // prefetch next tile; loads fly during compute
      const int kb2 = (jt + 1) * 64;
      const uint4* nk = (const uint4*)&kg[base + (size_t)(kb2 + krow) * Dd + kcg];
      const uint4* nv = (const uint4*)&vtg[base + (size_t)krow * Tt + kb2 + kcg];
      rk0 = nk[0]; rk1 = nk[1];
      rv0 = nv[0]; rv1 = nv[1];
    }
    __syncthreads();  // bank jt&1 visible; also orders next write of other bank

    if (jt > jt_diag) continue;  // wave past its causal range (barriers stay matched)
    const int kb = jt * 64;

    // S^T tile t: A = permuted K rows t*16+l16, B = Q. C-layout: col l16 = q,
    // row quad*4+r -> key kc = kb + (t>>1)*32 + quad*8 + (t&1)*4 + r.
    f32x4 sS[4];
    __builtin_amdgcn_s_setprio(1);
#pragma unroll
    for (int t = 0; t < 4; ++t) {
      const bf16x8 kf0 = *(const bf16x8*)&sKb[swz64(t * 16 + l16, quad * 8)];
      const bf16x8 kf1 = *(const bf16x8*)&sKb[swz64(t * 16 + l16, 32 + quad * 8)];
      sS[t] = mfma16(kf0, qf0, f32x4{0.f, 0.f, 0.f, 0.f});
      sS[t] = mfma16(kf1, qf1, sS[t]);
    }
    __builtin_amdgcn_s_setprio(0);

    if (jt == jt_diag) {  // boundary tile: causal mask
      const int q = qrow0 + l16;
#pragma unroll
      for (int t = 0; t < 4; ++t) {
        const int kc0 = kb + (t >> 1) * 32 + quad * 8 + (t & 1) * 4;
#pragma unroll
        for (int r = 0; r < 4; ++r)
          if (kc0 + r > q) sS[t][r] = NEG_INF;
      }
    }

    // p = exp(S-12) packed into K=32 A-frags (kc = cc*32 + quad*8 + j)
    bf16x8 pf[2];
#pragma unroll
    for (int cc = 0; cc < 2; ++cc)
#pragma unroll
      for (int j = 0; j < 8; ++j)
        pf[cc][j] = (__bf16)__expf(sS[cc * 2 + (j >> 2)][j & 3] - 12.0f);

    // PV + rowsum, K=32. vb: V^T row dt*16+l16, cols cc*32+quad*8.
    __builtin_amdgcn_s_setprio(1);
#pragma unroll
    for (int cc = 0; cc < 2; ++cc) {
#pragma unroll
      for (int dt = 0; dt < 4; ++dt) {
        const bf16x8 vb =
            *(const bf16x8*)&sVb[swz64(dt * 16 + l16, cc * 32 + quad * 8)];
        o[dt] = mfma16(pf[cc], vb, o[dt]);
      }
      oL = mfma16(pf[cc], ones8, oL);
    }
    __builtin_amdgcn_s_setprio(0);
  }

  // epilogue: C-layout row quad*4+r = q, col dt*16+l16 = d
#pragma unroll
  for (int r = 0; r < 4; ++r) {
    const float inv = 1.0f / oL[r];
    const int trow = qrow0 + quad * 4 + r;
#pragma unroll
    for (int dt = 0; dt < 4; ++dt)
      yb[((size_t)(b * Tt + trow)) * Cc + h * Dd + dt * 16 + l16] =
          __float2bfloat16(o[dt][r] * inv);
  }
}

extern "C" void kernel_launch(void* const* d_in, const int* in_sizes, int n_in,
                              void* d_out, int out_size, void* d_ws, size_t ws_size,
                              hipStream_t stream) {
  (void)in_sizes; (void)n_in; (void)out_size; (void)ws_size;
  const float* x      = (const float*)d_in[0];
  const float* W_attn = (const float*)d_in[1];
  const float* b_attn = (const float*)d_in[2];
  const float* W_proj = (const float*)d_in[3];
  const float* b_proj = (const float*)d_in[4];
  float* out = (float*)d_out;

  constexpr size_t SZ_WA = (size_t)3072 * 1024;
  constexpr size_t SZ_WP = (size_t)1024 * 1024;
  constexpr size_t SZ_X  = (size_t)4096 * 1024;
  constexpr size_t SZ_T  = (size_t)Bb * Hh * Tt * Dd;

  BF16* ws   = (BF16*)d_ws;
  BF16* wtAb = ws;
  BF16* wtPb = wtAb + SZ_WA;
  BF16* xb   = wtPb + SZ_WP;
  BF16* q    = xb + SZ_X;
  BF16* k    = q + SZ_T;
  BF16* vt   = k + SZ_T;
  BF16* yb   = vt + SZ_T;

  prep_kernel<<<dim3(6144), 256, 0, stream>>>(x, xb, W_attn, wtAb, W_proj, wtPb);
  gemm_bt<0><<<dim3(24, 32), 256, 0, stream>>>(xb, wtAb, b_attn, q, k, vt, nullptr,
                                               3072, 1024);
  attn_kernel<<<dim3(1024), 256, 0, stream>>>(q, k, vt, yb);
  gemm_bt<1><<<dim3(8, 32), 256, 0, stream>>>(yb, wtPb, b_proj, nullptr, nullptr,
                                              nullptr, out, 1024, 1024);
}